// Round 6
// baseline (2495.204 us; speedup 1.0000x reference)
//
#include <hip/hip_runtime.h>

#define USER_NUM 100000
#define ITEM_NUM 50000
#define N_NODES  150000
#define EMB      64
#define NNZ      5000000
#define NELEM    (N_NODES * EMB)              // 9,600,000
#define RPB      128                          // rows per bucket
#define NBUCKET  ((N_NODES + RPB - 1) / RPB)  // 1172

typedef unsigned long long u64;

// ---------- ego0 = concat(user,item) (runs AFTER binning; A aliases stageA) ----------
__global__ void concat_kernel(const float* __restrict__ user,
                              const float* __restrict__ item,
                              float* __restrict__ A) {
    int i = blockIdx.x * blockDim.x + threadIdx.x;
    if (i >= NELEM / 4) return;
    int base = i * 4;
    const float* src = (base < USER_NUM * EMB) ? (user + base)
                                               : (item + (base - USER_NUM * EMB));
    *(float4*)(A + base) = *(const float4*)src;
}

// ---------- phase 1a: bucket histogram ----------
__global__ void bucket_count(const int* __restrict__ row, int* __restrict__ bucketcnt) {
    int e = blockIdx.x * blockDim.x + threadIdx.x;
    if (e >= NNZ) return;
    atomicAdd(&bucketcnt[row[e] >> 7], 1);
}

// ---------- phase 1b: exclusive scan over 1172 buckets (single block) ----------
__global__ void bucket_scan(const int* __restrict__ bucketcnt,
                            int* __restrict__ bucketoff, int* __restrict__ buckettail) {
    __shared__ int sdata[NBUCKET + 1];
    int t = threadIdx.x;
    for (int i = t; i < NBUCKET; i += blockDim.x) sdata[i] = bucketcnt[i];
    __syncthreads();
    if (t == 0) {
        int run = 0;
        for (int b = 0; b < NBUCKET; ++b) { int x = sdata[b]; sdata[b] = run; run += x; }
        sdata[NBUCKET] = run;
    }
    __syncthreads();
    for (int i = t; i <= NBUCKET; i += blockDim.x) {
        bucketoff[i] = sdata[i];
        if (i < NBUCKET) buckettail[i] = sdata[i];
    }
}

// ---------- phase 1c: bin edges into bucket regions (1172 append streams, L2-resident) ----------
__global__ void binA_kernel(const int* __restrict__ row, const int* __restrict__ col,
                            const float* __restrict__ vals,
                            int* __restrict__ buckettail, u64* __restrict__ stageA) {
    int e = blockIdx.x * blockDim.x + threadIdx.x;
    if (e >= NNZ) return;
    int r = row[e];
    int b = r >> 7;
    int pos = atomicAdd(&buckettail[b], 1);
    u64 p = ((u64)(unsigned)__float_as_int(vals[e]) << 32)
          | ((u64)(r & 127) << 18) | (unsigned)col[e];
    stageA[pos] = p;
}

// ---------- phase 1d: within-bucket row sort (one block per bucket; writes L2-local) ----------
__global__ __launch_bounds__(256) void binB_kernel(const int* __restrict__ bucketoff,
                            const u64* __restrict__ stageA,
                            int2* __restrict__ sedge, int* __restrict__ rowend) {
    int b = blockIdx.x;
    int s = bucketoff[b], e = bucketoff[b + 1];
    int tid = threadIdx.x;
    int rows_here = N_NODES - b * RPB; if (rows_here > RPB) rows_here = RPB;
    __shared__ int hist[RPB];
    __shared__ int cursor[RPB + 1];
    if (tid < RPB) hist[tid] = 0;
    __syncthreads();
    for (int i = s + tid; i < e; i += 256) {
        u64 p = stageA[i];
        atomicAdd(&hist[(int)(p >> 18) & 127], 1);
    }
    __syncthreads();
    if (tid == 0) {
        int run = 0;
        for (int r = 0; r < RPB; ++r) { cursor[r] = run; run += hist[r]; }
        cursor[RPB] = run;
    }
    __syncthreads();
    if (tid < rows_here) rowend[b * RPB + tid] = s + cursor[tid + 1];
    __syncthreads();
    for (int i = s + tid; i < e; i += 256) {
        u64 p = stageA[i];
        int lr = (int)(p >> 18) & 127;
        int pos = atomicAdd(&cursor[lr], 1);
        int2 o; o.x = (int)(p & 0x3FFFF); o.y = (int)(p >> 32);
        sedge[s + pos] = o;
    }
}

// ---------- phase 2: one wave per destination row (unchanged from round 5) ----------
// MODE 1: acc = x[o] + s ; ynext = s     (x = ego0)
// MODE 2: acc += s       ; ynext = s
// MODE 3: acc = (acc + s) * 0.25
template <int MODE>
__global__ __launch_bounds__(256) void spmm_row_kernel(
        const int* __restrict__ rowend,
        const int2* __restrict__ sedge,
        const float* __restrict__ x,
        float* __restrict__ ynext, float* __restrict__ acc) {
    int wave = threadIdx.x >> 6;
    int lane = threadIdx.x & 63;
    int r = blockIdx.x * 4 + wave;
    if (r >= N_NODES) return;
    int start = (r == 0) ? 0 : rowend[r - 1];
    int end = rowend[r];
    float s = 0.f;
    for (int base = start; base < end; base += 64) {
        int n = end - base; if (n > 64) n = 64;
        int c = 0; float v = 0.f;
        if (lane < n) {
            int2 p = sedge[base + lane];
            c = p.x; v = __int_as_float(p.y);
        }
        int j = 0;
        for (; j + 8 <= n; j += 8) {
            int   c0 = __shfl(c, j),     c1 = __shfl(c, j + 1);
            int   c2 = __shfl(c, j + 2), c3 = __shfl(c, j + 3);
            int   c4 = __shfl(c, j + 4), c5 = __shfl(c, j + 5);
            int   c6 = __shfl(c, j + 6), c7 = __shfl(c, j + 7);
            float v0 = __shfl(v, j),     v1 = __shfl(v, j + 1);
            float v2 = __shfl(v, j + 2), v3 = __shfl(v, j + 3);
            float v4 = __shfl(v, j + 4), v5 = __shfl(v, j + 5);
            float v6 = __shfl(v, j + 6), v7 = __shfl(v, j + 7);
            float x0 = x[c0 * EMB + lane];
            float x1 = x[c1 * EMB + lane];
            float x2 = x[c2 * EMB + lane];
            float x3 = x[c3 * EMB + lane];
            float x4 = x[c4 * EMB + lane];
            float x5 = x[c5 * EMB + lane];
            float x6 = x[c6 * EMB + lane];
            float x7 = x[c7 * EMB + lane];
            s += v0 * x0; s += v1 * x1; s += v2 * x2; s += v3 * x3;
            s += v4 * x4; s += v5 * x5; s += v6 * x6; s += v7 * x7;
        }
        for (; j < n; ++j) {
            int   cj = __shfl(c, j);
            float vj = __shfl(v, j);
            s += vj * x[cj * EMB + lane];
        }
    }
    int o = r * EMB + lane;
    if (MODE == 1) {
        ynext[o] = s;
        acc[o] = x[o] + s;
    } else if (MODE == 2) {
        ynext[o] = s;
        acc[o] += s;
    } else {
        acc[o] = (acc[o] + s) * 0.25f;
    }
}

extern "C" void kernel_launch(void* const* d_in, const int* in_sizes, int n_in,
                              void* d_out, int out_size, void* d_ws, size_t ws_size,
                              hipStream_t stream) {
    const float* user = (const float*)d_in[0];
    const float* item = (const float*)d_in[1];
    const int*   row  = (const int*)d_in[2];
    const int*   col  = (const int*)d_in[3];
    const float* vals = (const float*)d_in[4];

    float* A          = (float*)d_ws;             // 38.4 MB (ego0 / layer-2 out)
    float* B          = A + NELEM;                // 38.4 MB
    int2*  sedge      = (int2*)(B + NELEM);       // 40 MB final row-sorted edges
    int*   rowend     = (int*)(sedge + NNZ);      // 0.6 MB
    int*   bucketcnt  = rowend + N_NODES;         // 1172
    int*   bucketoff  = bucketcnt + NBUCKET;      // 1173
    int*   buckettail = bucketoff + NBUCKET + 1;  // 1172
    u64*   stageA     = (u64*)d_ws;               // 40 MB, aliases A (+1.6 MB of B)
    float* acc        = (float*)d_out;

    const int eb = 256;
    const int egrid = (NNZ + eb - 1) / eb;        // 19532
    const int cgrid = (NELEM / 4 + eb - 1) / eb;  // 9375
    const int rgrid = N_NODES / 4;                // 37500

    hipMemsetAsync(bucketcnt, 0, NBUCKET * sizeof(int), stream);
    bucket_count<<<egrid, eb, 0, stream>>>(row, bucketcnt);
    bucket_scan<<<1, 1024, 0, stream>>>(bucketcnt, bucketoff, buckettail);
    binA_kernel<<<egrid, eb, 0, stream>>>(row, col, vals, buckettail, stageA);
    binB_kernel<<<NBUCKET, eb, 0, stream>>>(bucketoff, stageA, sedge, rowend);
    // stageA dead from here; A/B usable
    concat_kernel<<<cgrid, eb, 0, stream>>>(user, item, A);

    // layer 1: ego0(A) -> B ; acc = A + B
    spmm_row_kernel<1><<<rgrid, eb, 0, stream>>>(rowend, sedge, A, B, acc);
    // layer 2: B -> A ; acc += A
    spmm_row_kernel<2><<<rgrid, eb, 0, stream>>>(rowend, sedge, B, A, acc);
    // layer 3: A -> (fused finalize) ; acc = (acc + s) * 0.25
    spmm_row_kernel<3><<<rgrid, eb, 0, stream>>>(rowend, sedge, A, nullptr, acc);
}

// Round 7
// 1155.531 us; speedup vs baseline: 2.1594x; 2.1594x over previous
//
#include <hip/hip_runtime.h>

#define USER_NUM 100000
#define ITEM_NUM 50000
#define N_NODES  150000
#define EMB      64
#define NNZ      5000000
#define NELEM    (N_NODES * EMB)           // 9,600,000
#define NPART    ((N_NODES + 255) / 256)   // 586

// XCD slicing: 16-row granules so each 64B counter/stream-tail line maps to one slice
#define G8       160                        // blocks per slice
#define CHUNK    ((NNZ + G8 - 1) / G8)      // 31250
__device__ __forceinline__ int slice_of(int r) { return (r >> 4) & 7; }

// ---------- ego0 = concat(user,item) ----------
__global__ void concat_kernel(const float* __restrict__ user,
                              const float* __restrict__ item,
                              float* __restrict__ A) {
    int i = blockIdx.x * blockDim.x + threadIdx.x;
    if (i >= NELEM / 4) return;
    int base = i * 4;
    const float* src = (base < USER_NUM * EMB) ? (user + base)
                                               : (item + (base - USER_NUM * EMB));
    *(float4*)(A + base) = *(const float4*)src;
}

// ---------- phase 1a: per-row histogram, XCD-sliced ----------
__global__ void count_sliced(const int* __restrict__ row, int* __restrict__ rowcnt) {
    int slice = blockIdx.x & 7;
    int j = blockIdx.x >> 3;
    int base = j * CHUNK;
    int end = base + CHUNK; if (end > NNZ) end = NNZ;
    for (int e = base + threadIdx.x; e < end; e += 256) {
        int r = row[e];
        if (slice_of(r) == slice) atomicAdd(&rowcnt[r], 1);
    }
}

// ---------- phase 1b: exclusive scan of rowcnt -> rowoff (3 kernels, as round 4) ----------
__global__ void scan_blocks(const int* __restrict__ rowcnt, int* __restrict__ part) {
    __shared__ int sdata[256];
    int i = blockIdx.x * 256 + threadIdx.x;
    sdata[threadIdx.x] = (i < N_NODES) ? rowcnt[i] : 0;
    __syncthreads();
    for (int ofs = 128; ofs > 0; ofs >>= 1) {
        if (threadIdx.x < ofs) sdata[threadIdx.x] += sdata[threadIdx.x + ofs];
        __syncthreads();
    }
    if (threadIdx.x == 0) part[blockIdx.x] = sdata[0];
}

__global__ void scan_partials(int* __restrict__ part) {
    __shared__ int sdata[NPART];
    int t = threadIdx.x;
    for (int i = t; i < NPART; i += blockDim.x) sdata[i] = part[i];
    __syncthreads();
    if (t == 0) {
        int run = 0;
        for (int b = 0; b < NPART; ++b) { int x = sdata[b]; sdata[b] = run; run += x; }
    }
    __syncthreads();
    for (int i = t; i < NPART; i += blockDim.x) part[i] = sdata[i];
}

__global__ void scan_final(const int* __restrict__ rowcnt, const int* __restrict__ part,
                           int* __restrict__ rowoff) {
    __shared__ int sdata[256];
    int i = blockIdx.x * 256 + threadIdx.x;
    int vcur = (i < N_NODES) ? rowcnt[i] : 0;
    sdata[threadIdx.x] = vcur;
    __syncthreads();
    for (int ofs = 1; ofs < 256; ofs <<= 1) {
        int t = (threadIdx.x >= ofs) ? sdata[threadIdx.x - ofs] : 0;
        __syncthreads();
        sdata[threadIdx.x] += t;
        __syncthreads();
    }
    if (i < N_NODES) rowoff[i] = part[blockIdx.x] + sdata[threadIdx.x] - vcur;
}

// ---------- phase 1c: row-sorted scatter, XCD-sliced (tail lines L2-local per XCD) ----------
// mutates rowoff so that afterwards rowoff[r] == end-of-row-r
__global__ void scatter_sliced(const int* __restrict__ row, const int* __restrict__ col,
                               const float* __restrict__ vals,
                               int* __restrict__ rowoff, int2* __restrict__ sedge) {
    int slice = blockIdx.x & 7;
    int j = blockIdx.x >> 3;
    int base = j * CHUNK;
    int end = base + CHUNK; if (end > NNZ) end = NNZ;
    for (int e = base + threadIdx.x; e < end; e += 256) {
        int r = row[e];
        if (slice_of(r) == slice) {
            int pos = atomicAdd(&rowoff[r], 1);
            int2 p; p.x = col[e]; p.y = __float_as_int(vals[e]);
            sedge[pos] = p;
        }
    }
}

// ---------- phase 2: one wave per destination row, unroll-16 gather pipeline ----------
// MODE 1: acc = x[o] + s ; ynext = s     (x = ego0)
// MODE 2: acc += s       ; ynext = s
// MODE 3: acc = (acc + s) * 0.25
template <int MODE>
__global__ __launch_bounds__(256) void spmm_row_kernel(
        const int* __restrict__ rowend,
        const int2* __restrict__ sedge,
        const float* __restrict__ x,
        float* __restrict__ ynext, float* __restrict__ acc) {
    int wave = threadIdx.x >> 6;
    int lane = threadIdx.x & 63;
    int r = blockIdx.x * 4 + wave;
    if (r >= N_NODES) return;
    int start = (r == 0) ? 0 : rowend[r - 1];
    int end = rowend[r];
    float s = 0.f;
    for (int base = start; base < end; base += 64) {
        int n = end - base; if (n > 64) n = 64;
        int c = 0; float v = 0.f;
        if (lane < n) {
            int2 p = sedge[base + lane];
            c = p.x; v = __int_as_float(p.y);
        }
        int j = 0;
        for (; j + 16 <= n; j += 16) {
            int ck[16]; float vk[16];
#pragma unroll
            for (int k = 0; k < 16; ++k) { ck[k] = __shfl(c, j + k); vk[k] = __shfl(v, j + k); }
            float xk[16];
#pragma unroll
            for (int k = 0; k < 16; ++k) xk[k] = x[ck[k] * EMB + lane];
#pragma unroll
            for (int k = 0; k < 16; ++k) s += vk[k] * xk[k];
        }
        for (; j + 4 <= n; j += 4) {
            int   c0 = __shfl(c, j),     c1 = __shfl(c, j + 1);
            int   c2 = __shfl(c, j + 2), c3 = __shfl(c, j + 3);
            float v0 = __shfl(v, j),     v1 = __shfl(v, j + 1);
            float v2 = __shfl(v, j + 2), v3 = __shfl(v, j + 3);
            float x0 = x[c0 * EMB + lane];
            float x1 = x[c1 * EMB + lane];
            float x2 = x[c2 * EMB + lane];
            float x3 = x[c3 * EMB + lane];
            s += v0 * x0; s += v1 * x1; s += v2 * x2; s += v3 * x3;
        }
        for (; j < n; ++j) {
            int   cj = __shfl(c, j);
            float vj = __shfl(v, j);
            s += vj * x[cj * EMB + lane];
        }
    }
    int o = r * EMB + lane;
    if (MODE == 1) {
        ynext[o] = s;
        acc[o] = x[o] + s;
    } else if (MODE == 2) {
        ynext[o] = s;
        acc[o] += s;
    } else {
        acc[o] = (acc[o] + s) * 0.25f;
    }
}

extern "C" void kernel_launch(void* const* d_in, const int* in_sizes, int n_in,
                              void* d_out, int out_size, void* d_ws, size_t ws_size,
                              hipStream_t stream) {
    const float* user = (const float*)d_in[0];
    const float* item = (const float*)d_in[1];
    const int*   row  = (const int*)d_in[2];
    const int*   col  = (const int*)d_in[3];
    const float* vals = (const float*)d_in[4];

    float* A      = (float*)d_ws;            // 38.4 MB (ego0 / layer-2 out)
    float* B      = A + NELEM;               // 38.4 MB
    int2*  sedge  = (int2*)(B + NELEM);      // 40 MB row-sorted packed edges
    int*   rowcnt = (int*)(sedge + NNZ);     // 0.6 MB
    int*   rowoff = rowcnt + N_NODES;        // 0.6 MB -> becomes rowend after scatter
    int*   part   = rowoff + N_NODES;        // ~2.4 KB
    float* acc    = (float*)d_out;

    const int eb = 256;
    const int cgrid = (NELEM / 4 + eb - 1) / eb;  // 9375
    const int rgrid = N_NODES / 4;                // 37500
    const int sgrid = 8 * G8;                     // 1280 sliced blocks

    hipMemsetAsync(rowcnt, 0, N_NODES * sizeof(int), stream);
    count_sliced<<<sgrid, eb, 0, stream>>>(row, rowcnt);
    scan_blocks<<<NPART, 256, 0, stream>>>(rowcnt, part);
    scan_partials<<<1, 1024, 0, stream>>>(part);
    scan_final<<<NPART, 256, 0, stream>>>(rowcnt, part, rowoff);
    scatter_sliced<<<sgrid, eb, 0, stream>>>(row, col, vals, rowoff, sedge);
    // rowoff[r] is now end-of-row-r
    concat_kernel<<<cgrid, eb, 0, stream>>>(user, item, A);

    // layer 1: ego0(A) -> B ; acc = A + B
    spmm_row_kernel<1><<<rgrid, eb, 0, stream>>>(rowoff, sedge, A, B, acc);
    // layer 2: B -> A ; acc += A
    spmm_row_kernel<2><<<rgrid, eb, 0, stream>>>(rowoff, sedge, B, A, acc);
    // layer 3: A -> (fused finalize) ; acc = (acc + s) * 0.25
    spmm_row_kernel<3><<<rgrid, eb, 0, stream>>>(rowoff, sedge, A, nullptr, acc);
}